// Round 16
// baseline (115.927 us; speedup 1.0000x reference)
//
#include <hip/hip_runtime.h>
#include <hip/hip_bf16.h>

#define TEMP_INV (1.0f / 0.07f)
#define LOG2E 1.4426950408889634f
#define LN2 0.6931471805599453f
#define CFIX 21.0f

typedef __attribute__((ext_vector_type(4))) float f32x4;

__device__ __forceinline__ void gload16(const unsigned char* g,
                                        unsigned char* l) {
  __builtin_amdgcn_global_load_lds(
      (const __attribute__((address_space(1))) void*)g,
      (__attribute__((address_space(3))) void*)l, 16, 0, 0);
}

// ---------------- Kernel 1: L2-normalize -> fp8(e4m3) feats x16, cross, ------
// ---------------- zero lsum (folded). Verbatim R12 (proven). -----------------
__global__ __launch_bounds__(256) void norm_kernel(
    const float* __restrict__ A, const float* __restrict__ P,
    unsigned char* __restrict__ F, float* __restrict__ cross,
    float* __restrict__ lsum, int B, int D) {
  const int row = blockIdx.x;
  const int t = threadIdx.x;
  {
    const int zi = row * 256 + t;
    if (zi < 2 * B) lsum[zi] = 0.f;
  }
  const float4* a4 = reinterpret_cast<const float4*>(A + (size_t)row * D);
  const float4* p4 = reinterpret_cast<const float4*>(P + (size_t)row * D);
  const int n4 = D >> 2;
  float sa = 0.f, sp = 0.f, sx = 0.f;
  for (int i = t; i < n4; i += 256) {
    float4 av = a4[i], pv = p4[i];
    sa += av.x * av.x + av.y * av.y + av.z * av.z + av.w * av.w;
    sp += pv.x * pv.x + pv.y * pv.y + pv.z * pv.z + pv.w * pv.w;
    sx += av.x * pv.x + av.y * pv.y + av.z * pv.z + av.w * pv.w;
  }
#pragma unroll
  for (int off = 32; off; off >>= 1) {
    sa += __shfl_down(sa, off);
    sp += __shfl_down(sp, off);
    sx += __shfl_down(sx, off);
  }
  __shared__ float red[3][4];
  const int wid = t >> 6, lane = t & 63;
  if (lane == 0) { red[0][wid] = sa; red[1][wid] = sp; red[2][wid] = sx; }
  __syncthreads();
  sa = red[0][0] + red[0][1] + red[0][2] + red[0][3];
  sp = red[1][0] + red[1][1] + red[1][2] + red[1][3];
  sx = red[2][0] + red[2][1] + red[2][2] + red[2][3];
  const float ian = rsqrtf(sa), ipn = rsqrtf(sp);
  const float ia = ian * 16.f, ip = ipn * 16.f;  // x16 -> e4m3 range
  unsigned char* fa = F + (size_t)row * D;
  unsigned char* fp = F + (size_t)(B + row) * D;
  for (int i = t; i < n4; i += 256) {
    float4 av = a4[i], pv = p4[i];
    int qa = 0, qp = 0;
    qa = __builtin_amdgcn_cvt_pk_fp8_f32(av.x * ia, av.y * ia, qa, false);
    qa = __builtin_amdgcn_cvt_pk_fp8_f32(av.z * ia, av.w * ia, qa, true);
    qp = __builtin_amdgcn_cvt_pk_fp8_f32(pv.x * ip, pv.y * ip, qp, false);
    qp = __builtin_amdgcn_cvt_pk_fp8_f32(pv.z * ip, pv.w * ip, qp, true);
    reinterpret_cast<int*>(fa)[i] = qa;
    reinterpret_cast<int*>(fp)[i] = qp;
  }
  if (t == 0) cross[row] = sx * ian * ipn;
}

// =============== fp8 granule layout (R12-proven, 256 rows x 32 k = 8KB) ======
// line=r>>2; chunk c=(r&3)*2+(k>>4); phys p=c^(line&7);
// byte=line*128+p*16+(k&15). Frag-read formula proven absmax-0 R12/R14/R15.

// ---------------- Kernel 2a: full tiles, 1024 threads / 16 waves -------------
// 256x256 triangle tile, FULL K=1024. 16 waves of 64x64 (wr=w>>2 j-64,
// wn=w&3 i-64) -> 4 waves/SIMD: wave-level multiplex fills the post-barrier
// read-latency + MFMA serialization that capped 8-wave variants at ~25%
// MfmaUtil (R12/R14/R15). acc[4][4]=64 VGPR -> ~110 total, fits the 128 cap
// 16 waves/CU requires (R9 lesson: never exceed it).
// Pipeline = R12-proven 4-buffer drain: per K-64 iter {vmcnt(4); barrier;
// read frags; stage tile v+3 (2 loads/thread, addr-clamped so counts stay
// uniform; buf (v+3)&3 WAR-safe per R12's barrier argument); MFMA x32}.
__global__ __launch_bounds__(1024) void gram_full_kernel(
    const unsigned char* __restrict__ F, float* __restrict__ lsum, int NN,
    int D) {
  __shared__ unsigned char lds8[4][2][2][8192];  // [buf][A/B][KS][8KB]
  int lin = blockIdx.x;
  lin = (lin & 7) * 64 + (lin >> 3);  // XCD swizzle, 512 = 8*64 bijective
  int by = (int)((sqrtf(8.f * (float)lin + 1.f) - 1.f) * 0.5f);
  while ((by + 1) * (by + 2) / 2 <= lin) ++by;
  while (by * (by + 1) / 2 > lin) --by;
  const int bx = lin - by * (by + 1) / 2;  // bx <= by (never diag: diag tiles
  const int r0 = bx * 256;                 //  are lin>=512, half kernel)
  const int c0 = by * 256;
  const bool diag = (bx == by);

  const int t = threadIdx.x;
  const int lane = t & 63, w = t >> 6;  // w 0..15
  const int lo = lane & 15, hi = lane >> 4;
  const int wr = w >> 2, wn = w & 3;

  // staging: thread t stages A-chunk and B-chunk (t&511) of region KSa=t>>9
  const int KSa = t >> 9;
  const int cS = t & 511;
  const int lineS = cS >> 3, pS = (cS & 7) ^ (lineS & 7);
  const int trS = lineS * 4 + (pS >> 1);
  const int kcS = ((pS & 1) << 4) + KSa * 32;
  const unsigned char* sA = F + (size_t)(c0 + trS) * D + kcS;
  const unsigned char* sB = F + (size_t)(r0 + trS) * D + kcS;
  const int dstW = (w & 7) * 1024;  // wave-uniform byte base within region

  // fragment read byte offsets (R12-proven formula), 64x64 wave tile
  int offA[4], offB[4];
#pragma unroll
  for (int mf = 0; mf < 4; ++mf) {
    const int r = wr * 64 + mf * 16 + lo;
    const int lr = r >> 2;
    const int cu = ((r & 3) << 1) | (hi >> 1);
    offA[mf] = lr * 128 + ((cu ^ (lr & 7)) << 4) + ((hi & 1) << 3);
  }
#pragma unroll
  for (int nf = 0; nf < 4; ++nf) {
    const int r = wn * 64 + nf * 16 + lo;
    const int lr = r >> 2;
    const int cu = ((r & 3) << 1) | (hi >> 1);
    offB[nf] = lr * 128 + ((cu ^ (lr & 7)) << 4) + ((hi & 1) << 3);
  }

#define STAGE(V)                                                      \
  do {                                                                \
    int v_ = (V); if (v_ > 15) v_ = 15;                               \
    gload16(sA + v_ * 64, &lds8[(V) & 3][0][KSa][dstW]);              \
    gload16(sB + v_ * 64, &lds8[(V) & 3][1][KSa][dstW]);              \
  } while (0)

  f32x4 acc[4][4];
#pragma unroll
  for (int a = 0; a < 4; ++a)
#pragma unroll
    for (int bb = 0; bb < 4; ++bb) acc[a][bb] = (f32x4){0.f, 0.f, 0.f, 0.f};

  // prologue: tiles 0,1,2 staged (6 loads/thread in flight)
  STAGE(0); STAGE(1); STAGE(2);

  for (int v = 0; v < 16; ++v) {
    const int buf = v & 3;
    asm volatile("s_waitcnt vmcnt(4)" ::: "memory");  // tile v landed
    __builtin_amdgcn_s_barrier();
    asm volatile("" ::: "memory");

    long a0[4], a1[4], b0[4], b1[4];
#pragma unroll
    for (int q = 0; q < 4; ++q) {
      b0[q] = *(const long*)(&lds8[buf][1][0][0] + offB[q]);
      a0[q] = *(const long*)(&lds8[buf][0][0][0] + offA[q]);
      b1[q] = *(const long*)(&lds8[buf][1][1][0] + offB[q]);
      a1[q] = *(const long*)(&lds8[buf][0][1][0] + offA[q]);
    }

    STAGE(v + 3);  // clamped addr keeps per-wave vmcnt uniform

    __builtin_amdgcn_s_setprio(1);
#pragma unroll
    for (int mf = 0; mf < 4; ++mf)
#pragma unroll
      for (int nf = 0; nf < 4; ++nf)
        acc[mf][nf] = __builtin_amdgcn_mfma_f32_16x16x32_fp8_fp8(
            a0[mf], b0[nf], acc[mf][nf], 0, 0, 0);
#pragma unroll
    for (int mf = 0; mf < 4; ++mf)
#pragma unroll
      for (int nf = 0; nf < 4; ++nf)
        acc[mf][nf] = __builtin_amdgcn_mfma_f32_16x16x32_fp8_fp8(
            a1[mf], b1[nf], acc[mf][nf], 0, 0, 0);
    __builtin_amdgcn_s_setprio(0);
    asm volatile("" ::: "memory");
  }

  // ---- dual-side epilogue (proven mapping; 64x64 wave tile) ----
  // acc[mf][nf][rg]: j = c0 + wr*64 + mf*16 + hi*4 + rg
  //                  i = r0 + wn*64 + nf*16 + lo
  const float scl = LOG2E * TEMP_INV / 256.f;
  float s_i[4] = {0.f, 0.f, 0.f, 0.f};
  float s_j[16];
#pragma unroll
  for (int q = 0; q < 16; ++q) s_j[q] = 0.f;
  {
    const int dgb = (r0 + wn * 64) - (c0 + wr * 64);
#pragma unroll
    for (int nf = 0; nf < 4; ++nf) {
      const int dg = dgb + nf * 16 + lo;
#pragma unroll
      for (int mf = 0; mf < 4; ++mf)
#pragma unroll
        for (int rg = 0; rg < 4; ++rg) {
          const int jloc = mf * 16 + hi * 4 + rg;
          float e = exp2f(acc[mf][nf][rg] * scl - CFIX);
          if (diag && dg == jloc) e = 0.f;
          s_i[nf] += e;
          s_j[mf * 4 + rg] += e;
        }
    }
  }
#pragma unroll
  for (int nf = 0; nf < 4; ++nf) {
    float v = s_i[nf];
    v += __shfl_xor(v, 16);
    v += __shfl_xor(v, 32);
    if (hi == 0) atomicAdd(&lsum[r0 + wn * 64 + nf * 16 + lo], v);
  }
  if (!diag) {
#pragma unroll
    for (int q = 0; q < 16; ++q) {
      float v = s_j[q];
      v += __shfl_xor(v, 1);
      v += __shfl_xor(v, 2);
      v += __shfl_xor(v, 4);
      v += __shfl_xor(v, 8);
      if (lo == 0)
        atomicAdd(&lsum[c0 + wr * 64 + (q >> 2) * 16 + hi * 4 + (q & 3)], v);
    }
  }
  asm volatile("s_waitcnt vmcnt(0)" ::: "memory");  // drain clamped tail
#undef STAGE
}

// ---------------- Kernel 2b: half tiles (R15-proven 512-thread body) ---------
__global__ __launch_bounds__(512, 2) void gram_half_kernel(
    const unsigned char* __restrict__ F, float* __restrict__ lsum, int NN,
    int D) {
  __shared__ unsigned char LDSb[4][32768];
  unsigned char* LDS = &LDSb[0][0];
  const int MFN = 4;
  const int idx = blockIdx.x;  // 0..31
  const int lin = 512 + (idx >> 1);
  const int c0extra = (idx & 1) * 128;
  int by = (int)((sqrtf(8.f * (float)lin + 1.f) - 1.f) * 0.5f);
  while ((by + 1) * (by + 2) / 2 <= lin) ++by;
  while (by * (by + 1) / 2 > lin) --by;
  const int bx = lin - by * (by + 1) / 2;
  const int r0 = bx * 256;
  const int c0 = by * 256 + c0extra;
  const bool diag = (bx == by);

  const int t = threadIdx.x;
  const int lane = t & 63, w = t >> 6;
  const int lo = lane & 15, hi = lane >> 4;
  const int wr = w >> 2, wn = w & 3;

  const int ciA = t & (MFN * 64 - 1);
  const int lrA = ciA >> 3, cuA = (ciA & 7) ^ (lrA & 7);
  const int trA = lrA * 4 + (cuA >> 1), kcA = (cuA & 1) << 4;
  const int lrB = t >> 3, cuB = (t & 7) ^ (lrB & 7);
  const int trB = lrB * 4 + (cuB >> 1), kcB = (cuB & 1) << 4;
  const unsigned char* sA = F + (size_t)(c0 + trA) * D + kcA;
  const unsigned char* sB = F + (size_t)(r0 + trB) * D + kcB;
  const int dstA = (w % MFN) * 1024;
  const int dstB = w * 1024;

  int offA[MFN], offB[4];
#pragma unroll
  for (int mf = 0; mf < MFN; ++mf) {
    const int r = wr * (MFN * 16) + mf * 16 + lo;
    const int lr = r >> 2;
    const int cu = ((r & 3) << 1) | (hi >> 1);
    offA[mf] = lr * 128 + ((cu ^ (lr & 7)) << 4) + ((hi & 1) << 3);
  }
#pragma unroll
  for (int nf = 0; nf < 4; ++nf) {
    const int r = wn * 64 + nf * 16 + lo;
    const int lr = r >> 2;
    const int cu = ((r & 3) << 1) | (hi >> 1);
    offB[nf] = lr * 128 + ((cu ^ (lr & 7)) << 4) + ((hi & 1) << 3);
  }

#define STAGE(V, KS)                                                        \
  do {                                                                      \
    int v_ = (V); if (v_ > 15) v_ = 15;                                     \
    const int o_ = v_ * 64 + (KS) * 32;                                     \
    gload16(sA + o_, LDS + ((V) & 3) * 32768 + (KS) * 8192 + dstA);         \
    gload16(sB + o_, LDS + ((V) & 3) * 32768 + 16384 + (KS) * 8192 + dstB); \
  } while (0)

  f32x4 acc[MFN][4];
#pragma unroll
  for (int a = 0; a < MFN; ++a)
#pragma unroll
    for (int bb = 0; bb < 4; ++bb) acc[a][bb] = (f32x4){0.f, 0.f, 0.f, 0.f};

  STAGE(0, 0); STAGE(0, 1);
  STAGE(1, 0); STAGE(1, 1);
  STAGE(2, 0); STAGE(2, 1);

  for (int v = 0; v < 16; ++v) {
    const int buf = v & 3;
    asm volatile("s_waitcnt vmcnt(8)" ::: "memory");
    __builtin_amdgcn_s_barrier();
    asm volatile("" ::: "memory");

    const unsigned char* RA0 = LDS + buf * 32768;
    const unsigned char* RA1 = RA0 + 8192;
    const unsigned char* RB0 = RA0 + 16384;
    const unsigned char* RB1 = RB0 + 8192;
    long a0[MFN], a1[MFN], b0[4], b1[4];
#pragma unroll
    for (int nf = 0; nf < 4; ++nf) b0[nf] = *(const long*)(RB0 + offB[nf]);
#pragma unroll
    for (int mf = 0; mf < MFN; ++mf) a0[mf] = *(const long*)(RA0 + offA[mf]);
#pragma unroll
    for (int nf = 0; nf < 4; ++nf) b1[nf] = *(const long*)(RB1 + offB[nf]);
#pragma unroll
    for (int mf = 0; mf < MFN; ++mf) a1[mf] = *(const long*)(RA1 + offA[mf]);

    STAGE(v + 3, 0);
    STAGE(v + 3, 1);

    __builtin_amdgcn_s_setprio(1);
#pragma unroll
    for (int mf = 0; mf < MFN; ++mf)
#pragma unroll
      for (int nf = 0; nf < 4; ++nf)
        acc[mf][nf] = __builtin_amdgcn_mfma_f32_16x16x32_fp8_fp8(
            a0[mf], b0[nf], acc[mf][nf], 0, 0, 0);
#pragma unroll
    for (int mf = 0; mf < MFN; ++mf)
#pragma unroll
      for (int nf = 0; nf < 4; ++nf)
        acc[mf][nf] = __builtin_amdgcn_mfma_f32_16x16x32_fp8_fp8(
            a1[mf], b1[nf], acc[mf][nf], 0, 0, 0);
    __builtin_amdgcn_s_setprio(0);
    asm volatile("" ::: "memory");
  }

  const float scl = LOG2E * TEMP_INV / 256.f;
  float s_i[4] = {0.f, 0.f, 0.f, 0.f};
  float s_j[MFN * 4];
#pragma unroll
  for (int q = 0; q < MFN * 4; ++q) s_j[q] = 0.f;
  {
    const int jb2 = c0 + wr * (MFN * 16);
#pragma unroll
    for (int nf = 0; nf < 4; ++nf) {
      const int dg = (r0 + wn * 64 + nf * 16 + lo) - jb2;
#pragma unroll
      for (int mf = 0; mf < MFN; ++mf)
#pragma unroll
        for (int rg = 0; rg < 4; ++rg) {
          const int jloc = mf * 16 + hi * 4 + rg;
          float e = exp2f(acc[mf][nf][rg] * scl - CFIX);
          if (diag && dg == jloc) e = 0.f;
          s_i[nf] += e;
          s_j[mf * 4 + rg] += e;
        }
    }
  }
#pragma unroll
  for (int nf = 0; nf < 4; ++nf) {
    float v = s_i[nf];
    v += __shfl_xor(v, 16);
    v += __shfl_xor(v, 32);
    if (hi == 0) atomicAdd(&lsum[r0 + wn * 64 + nf * 16 + lo], v);
  }
  if (!diag) {
#pragma unroll
    for (int q = 0; q < MFN * 4; ++q) {
      float v = s_j[q];
      v += __shfl_xor(v, 1);
      v += __shfl_xor(v, 2);
      v += __shfl_xor(v, 4);
      v += __shfl_xor(v, 8);
      if (lo == 0)
        atomicAdd(&lsum[c0 + wr * (MFN * 16) + (q >> 2) * 16 + hi * 4 +
                        (q & 3)],
                  v);
    }
  }
  asm volatile("s_waitcnt vmcnt(0)" ::: "memory");
#undef STAGE
}

// ---------------- Kernel 3a: per-row loss -> per-block partial sums ----------
__global__ __launch_bounds__(256) void finalize_part(
    const float* __restrict__ lsum, const float* __restrict__ cross,
    const int* __restrict__ labels, float* __restrict__ bsum,
    float* __restrict__ bcnt, int B) {
  const int NN = 2 * B;
  const int i = blockIdx.x * 256 + threadIdx.x;
  float sum = 0.f, cnt = 0.f;
  if (i < NN) {
    const float lse = LN2 * (CFIX + log2f(lsum[i]));
    const float lab = (float)labels[i % B];
    sum = (lse - cross[i % B] * TEMP_INV) * lab;
    cnt = lab;
  }
#pragma unroll
  for (int off = 32; off; off >>= 1) {
    sum += __shfl_down(sum, off);
    cnt += __shfl_down(cnt, off);
  }
  __shared__ float rs[4], rc[4];
  const int wid = threadIdx.x >> 6, lane = threadIdx.x & 63;
  if (lane == 0) { rs[wid] = sum; rc[wid] = cnt; }
  __syncthreads();
  if (threadIdx.x == 0) {
    bsum[blockIdx.x] = rs[0] + rs[1] + rs[2] + rs[3];
    bcnt[blockIdx.x] = rc[0] + rc[1] + rc[2] + rc[3];
  }
}

// ---------------- Kernel 3b: final reduce ------------------------------------
__global__ __launch_bounds__(64) void finalize_final(
    const float* __restrict__ bsum, const float* __restrict__ bcnt,
    float* __restrict__ out, int nb) {
  const int t = threadIdx.x;
  float s = (t < nb) ? bsum[t] : 0.f;
  float c = (t < nb) ? bcnt[t] : 0.f;
#pragma unroll
  for (int off = 32; off; off >>= 1) {
    s += __shfl_down(s, off);
    c += __shfl_down(c, off);
  }
  if (t == 0) out[0] = (c > 0.f) ? s / c : 0.f;
}

extern "C" void kernel_launch(void* const* d_in, const int* in_sizes, int n_in,
                              void* d_out, int out_size, void* d_ws, size_t ws_size,
                              hipStream_t stream) {
  const float* A = (const float*)d_in[0];
  const float* P = (const float*)d_in[1];
  const int* labels = (const int*)d_in[2];
  float* out = (float*)d_out;
  const int B = in_sizes[2];
  const int D = in_sizes[0] / B;
  const int NN = 2 * B;

  char* ws = (char*)d_ws;
  unsigned char* F = (unsigned char*)ws;
  size_t off = (size_t)NN * D;  // fp8: 1 B/elem
  off = (off + 255) & ~(size_t)255;
  float* cross = (float*)(ws + off);
  off += (size_t)B * sizeof(float);
  off = (off + 255) & ~(size_t)255;
  float* lsum = (float*)(ws + off);
  off += (size_t)NN * sizeof(float);
  off = (off + 255) & ~(size_t)255;
  float* bsum = (float*)(ws + off);
  off += 64 * sizeof(float);
  float* bcnt = (float*)(ws + off);

  norm_kernel<<<B, 256, 0, stream>>>(A, P, F, cross, lsum, B, D);
  // 528 triangle tiles = 512 full (16-wave kernel) + 16 tail tiles as
  // 32 j-halves (512-thread kernel; serialized after = the 3rd round anyway)
  gram_full_kernel<<<512, 1024, 0, stream>>>(F, lsum, NN, D);
  gram_half_kernel<<<32, 512, 0, stream>>>(F, lsum, NN, D);
  const int nb = (NN + 255) / 256;  // 32
  finalize_part<<<nb, 256, 0, stream>>>(lsum, cross, labels, bsum, bcnt, B);
  finalize_final<<<1, 64, 0, stream>>>(bsum, bcnt, out, nb);
}

// Round 17
// 115.663 us; speedup vs baseline: 1.0023x; 1.0023x over previous
//
#include <hip/hip_runtime.h>
#include <hip/hip_bf16.h>

#define TEMP_INV (1.0f / 0.07f)
#define LOG2E 1.4426950408889634f
#define LN2 0.6931471805599453f
#define CFIX 21.0f

typedef __attribute__((ext_vector_type(4))) float f32x4;

__device__ __forceinline__ void gload16(const unsigned char* g,
                                        unsigned char* l) {
  __builtin_amdgcn_global_load_lds(
      (const __attribute__((address_space(1))) void*)g,
      (__attribute__((address_space(3))) void*)l, 16, 0, 0);
}

// ---------------- Kernel 1: L2-normalize -> fp8(e4m3) feats x16, cross, ------
// ---------------- zero lsum (folded). Verbatim R12 (proven). -----------------
__global__ __launch_bounds__(256) void norm_kernel(
    const float* __restrict__ A, const float* __restrict__ P,
    unsigned char* __restrict__ F, float* __restrict__ cross,
    float* __restrict__ lsum, int B, int D) {
  const int row = blockIdx.x;
  const int t = threadIdx.x;
  {
    const int zi = row * 256 + t;
    if (zi < 2 * B) lsum[zi] = 0.f;
  }
  const float4* a4 = reinterpret_cast<const float4*>(A + (size_t)row * D);
  const float4* p4 = reinterpret_cast<const float4*>(P + (size_t)row * D);
  const int n4 = D >> 2;
  float sa = 0.f, sp = 0.f, sx = 0.f;
  for (int i = t; i < n4; i += 256) {
    float4 av = a4[i], pv = p4[i];
    sa += av.x * av.x + av.y * av.y + av.z * av.z + av.w * av.w;
    sp += pv.x * pv.x + pv.y * pv.y + pv.z * pv.z + pv.w * pv.w;
    sx += av.x * pv.x + av.y * pv.y + av.z * pv.z + av.w * pv.w;
  }
#pragma unroll
  for (int off = 32; off; off >>= 1) {
    sa += __shfl_down(sa, off);
    sp += __shfl_down(sp, off);
    sx += __shfl_down(sx, off);
  }
  __shared__ float red[3][4];
  const int wid = t >> 6, lane = t & 63;
  if (lane == 0) { red[0][wid] = sa; red[1][wid] = sp; red[2][wid] = sx; }
  __syncthreads();
  sa = red[0][0] + red[0][1] + red[0][2] + red[0][3];
  sp = red[1][0] + red[1][1] + red[1][2] + red[1][3];
  sx = red[2][0] + red[2][1] + red[2][2] + red[2][3];
  const float ian = rsqrtf(sa), ipn = rsqrtf(sp);
  const float ia = ian * 16.f, ip = ipn * 16.f;  // x16 -> e4m3 range
  unsigned char* fa = F + (size_t)row * D;
  unsigned char* fp = F + (size_t)(B + row) * D;
  for (int i = t; i < n4; i += 256) {
    float4 av = a4[i], pv = p4[i];
    int qa = 0, qp = 0;
    qa = __builtin_amdgcn_cvt_pk_fp8_f32(av.x * ia, av.y * ia, qa, false);
    qa = __builtin_amdgcn_cvt_pk_fp8_f32(av.z * ia, av.w * ia, qa, true);
    qp = __builtin_amdgcn_cvt_pk_fp8_f32(pv.x * ip, pv.y * ip, qp, false);
    qp = __builtin_amdgcn_cvt_pk_fp8_f32(pv.z * ip, pv.w * ip, qp, true);
    reinterpret_cast<int*>(fa)[i] = qa;
    reinterpret_cast<int*>(fp)[i] = qp;
  }
  if (t == 0) cross[row] = sx * ian * ipn;
}

// =============== fp8 granule layout (R12-proven, 256 rows x 32 k = 8KB) ======
// line=r>>2; chunk c=(r&3)*2+(k>>4); phys p=c^(line&7);
// byte=line*128+p*16+(k&15). Frag-read formula proven absmax-0 R12/R14-R16.

// ---------------- Tile body: 256x256 full tile, 16 waves (R16-proven) --------
// 16 waves of 64x64 (wr=w>>2 j-64, wn=w&3 i-64) -> 4 waves/SIMD wave-level
// multiplex. acc[4][4]=64 VGPR (R16 measured VGPR=64, no spill).
// Pipeline = R12-proven 4-buffer drain: per K-64 iter {vmcnt(4); barrier;
// read frags; stage tile v+3 (2 loads/thread, addr-clamped so counts stay
// uniform; buf (v+3)&3 WAR-safe per R12's barrier argument); MFMA x32}.
// Ends with vmcnt(0)+barrier so a following tile's prologue is WAR-safe
// (R10-proven inter-tile discipline).
__device__ __forceinline__ void gram_tile(
    unsigned char* LDS8, const unsigned char* F, float* lsum, int D,
    int r0, int c0, bool diag) {
  // LDS regions: buf*32768 + ab*16384 + KS*8192
  const int t = threadIdx.x;
  const int lane = t & 63, w = t >> 6;  // w 0..15
  const int lo = lane & 15, hi = lane >> 4;
  const int wr = w >> 2, wn = w & 3;

  // staging: thread t stages A-chunk and B-chunk (t&511) of region KSa=t>>9
  const int KSa = t >> 9;
  const int cS = t & 511;
  const int lineS = cS >> 3, pS = (cS & 7) ^ (lineS & 7);
  const int trS = lineS * 4 + (pS >> 1);
  const int kcS = ((pS & 1) << 4) + KSa * 32;
  const unsigned char* sA = F + (size_t)(c0 + trS) * D + kcS;
  const unsigned char* sB = F + (size_t)(r0 + trS) * D + kcS;
  const int dstW = (w & 7) * 1024;  // wave-uniform byte base within region

  // fragment read byte offsets (R12-proven formula), 64x64 wave tile
  int offA[4], offB[4];
#pragma unroll
  for (int mf = 0; mf < 4; ++mf) {
    const int r = wr * 64 + mf * 16 + lo;
    const int lr = r >> 2;
    const int cu = ((r & 3) << 1) | (hi >> 1);
    offA[mf] = lr * 128 + ((cu ^ (lr & 7)) << 4) + ((hi & 1) << 3);
  }
#pragma unroll
  for (int nf = 0; nf < 4; ++nf) {
    const int r = wn * 64 + nf * 16 + lo;
    const int lr = r >> 2;
    const int cu = ((r & 3) << 1) | (hi >> 1);
    offB[nf] = lr * 128 + ((cu ^ (lr & 7)) << 4) + ((hi & 1) << 3);
  }

#define STAGE(V)                                                        \
  do {                                                                  \
    int v_ = (V); if (v_ > 15) v_ = 15;                                 \
    gload16(sA + v_ * 64,                                               \
            LDS8 + ((V) & 3) * 32768 + KSa * 8192 + dstW);              \
    gload16(sB + v_ * 64,                                               \
            LDS8 + ((V) & 3) * 32768 + 16384 + KSa * 8192 + dstW);      \
  } while (0)

  f32x4 acc[4][4];
#pragma unroll
  for (int a = 0; a < 4; ++a)
#pragma unroll
    for (int bb = 0; bb < 4; ++bb) acc[a][bb] = (f32x4){0.f, 0.f, 0.f, 0.f};

  // prologue: tiles 0,1,2 staged (6 loads/thread in flight)
  STAGE(0); STAGE(1); STAGE(2);

  for (int v = 0; v < 16; ++v) {
    const int buf = v & 3;
    asm volatile("s_waitcnt vmcnt(4)" ::: "memory");  // tile v landed
    __builtin_amdgcn_s_barrier();
    asm volatile("" ::: "memory");

    long a0[4], a1[4], b0[4], b1[4];
#pragma unroll
    for (int q = 0; q < 4; ++q) {
      b0[q] = *(const long*)(LDS8 + buf * 32768 + 16384 + offB[q]);
      a0[q] = *(const long*)(LDS8 + buf * 32768 + offA[q]);
      b1[q] = *(const long*)(LDS8 + buf * 32768 + 16384 + 8192 + offB[q]);
      a1[q] = *(const long*)(LDS8 + buf * 32768 + 8192 + offA[q]);
    }

    STAGE(v + 3);  // clamped addr keeps per-wave vmcnt uniform

    __builtin_amdgcn_s_setprio(1);
#pragma unroll
    for (int mf = 0; mf < 4; ++mf)
#pragma unroll
      for (int nf = 0; nf < 4; ++nf)
        acc[mf][nf] = __builtin_amdgcn_mfma_f32_16x16x32_fp8_fp8(
            a0[mf], b0[nf], acc[mf][nf], 0, 0, 0);
#pragma unroll
    for (int mf = 0; mf < 4; ++mf)
#pragma unroll
      for (int nf = 0; nf < 4; ++nf)
        acc[mf][nf] = __builtin_amdgcn_mfma_f32_16x16x32_fp8_fp8(
            a1[mf], b1[nf], acc[mf][nf], 0, 0, 0);
    __builtin_amdgcn_s_setprio(0);
    asm volatile("" ::: "memory");
  }

  // ---- dual-side epilogue (proven mapping; 64x64 wave tile) ----
  // acc[mf][nf][rg]: j = c0 + wr*64 + mf*16 + hi*4 + rg
  //                  i = r0 + wn*64 + nf*16 + lo
  const float scl = LOG2E * TEMP_INV / 256.f;
  float s_i[4] = {0.f, 0.f, 0.f, 0.f};
  float s_j[16];
#pragma unroll
  for (int q = 0; q < 16; ++q) s_j[q] = 0.f;
  {
    const int dgb = (r0 + wn * 64) - (c0 + wr * 64);
#pragma unroll
    for (int nf = 0; nf < 4; ++nf) {
      const int dg = dgb + nf * 16 + lo;
#pragma unroll
      for (int mf = 0; mf < 4; ++mf)
#pragma unroll
        for (int rg = 0; rg < 4; ++rg) {
          const int jloc = mf * 16 + hi * 4 + rg;
          float e = exp2f(acc[mf][nf][rg] * scl - CFIX);
          if (diag && dg == jloc) e = 0.f;
          s_i[nf] += e;
          s_j[mf * 4 + rg] += e;
        }
    }
  }
#pragma unroll
  for (int nf = 0; nf < 4; ++nf) {
    float v = s_i[nf];
    v += __shfl_xor(v, 16);
    v += __shfl_xor(v, 32);
    if (hi == 0) atomicAdd(&lsum[r0 + wn * 64 + nf * 16 + lo], v);
  }
  if (!diag) {
#pragma unroll
    for (int q = 0; q < 16; ++q) {
      float v = s_j[q];
      v += __shfl_xor(v, 1);
      v += __shfl_xor(v, 2);
      v += __shfl_xor(v, 4);
      v += __shfl_xor(v, 8);
      if (lo == 0)
        atomicAdd(&lsum[c0 + wr * 64 + (q >> 2) * 16 + hi * 4 + (q & 3)], v);
    }
  }
  // inter-tile / exit drain: stale clamped stages must land before any
  // subsequent prologue overwrites their LDS bytes (R10-proven discipline)
  asm volatile("s_waitcnt vmcnt(0)" ::: "memory");
  __builtin_amdgcn_s_barrier();
  asm volatile("" ::: "memory");
#undef STAGE
}

// ---------------- Kernel 2: packed triangular Gram, makespan-balanced --------
// 528 tiles over 512 blocks: blocks 0-15 run tiles {b, 512+b} (the 16 extras
// = the last/diagonal-most tiles), blocks 16-511 run tile {b}. Heavy blocks
// sit at the FRONT of the dispatch order -> they occupy 16 CUs for ~2T while
// the 496 light blocks pack the remaining 240+256 slots in two waves ->
// makespan ~2T (vs 2T + serialized half-kernel in R16).
__global__ __launch_bounds__(1024) void gram_full_kernel(
    const unsigned char* __restrict__ F, float* __restrict__ lsum, int NN,
    int D) {
  __shared__ unsigned char lds8[4][2][2][8192];  // 128 KB
  const int bid = blockIdx.x;
  const int nT = (bid < 16) ? 2 : 1;

  for (int ti = 0; ti < nT; ++ti) {
    int lin;
    if (ti == 0) {
      lin = bid;
      lin = (lin & 7) * 64 + (lin >> 3);  // XCD swizzle, 512 = 8*64 bijective
    } else {
      lin = 512 + bid;  // extras: tiles 512..527
    }
    int by = (int)((sqrtf(8.f * (float)lin + 1.f) - 1.f) * 0.5f);
    while ((by + 1) * (by + 2) / 2 <= lin) ++by;
    while (by * (by + 1) / 2 > lin) --by;
    const int bx = lin - by * (by + 1) / 2;  // bx <= by
    const int r0 = bx * 256;
    const int c0 = by * 256;
    const bool diag = (bx == by);
    gram_tile(&lds8[0][0][0][0], F, lsum, D, r0, c0, diag);
  }
}

// ---------------- Kernel 3a: per-row loss -> per-block partial sums ----------
__global__ __launch_bounds__(256) void finalize_part(
    const float* __restrict__ lsum, const float* __restrict__ cross,
    const int* __restrict__ labels, float* __restrict__ bsum,
    float* __restrict__ bcnt, int B) {
  const int NN = 2 * B;
  const int i = blockIdx.x * 256 + threadIdx.x;
  float sum = 0.f, cnt = 0.f;
  if (i < NN) {
    const float lse = LN2 * (CFIX + log2f(lsum[i]));
    const float lab = (float)labels[i % B];
    sum = (lse - cross[i % B] * TEMP_INV) * lab;
    cnt = lab;
  }
#pragma unroll
  for (int off = 32; off; off >>= 1) {
    sum += __shfl_down(sum, off);
    cnt += __shfl_down(cnt, off);
  }
  __shared__ float rs[4], rc[4];
  const int wid = threadIdx.x >> 6, lane = threadIdx.x & 63;
  if (lane == 0) { rs[wid] = sum; rc[wid] = cnt; }
  __syncthreads();
  if (threadIdx.x == 0) {
    bsum[blockIdx.x] = rs[0] + rs[1] + rs[2] + rs[3];
    bcnt[blockIdx.x] = rc[0] + rc[1] + rc[2] + rc[3];
  }
}

// ---------------- Kernel 3b: final reduce ------------------------------------
__global__ __launch_bounds__(64) void finalize_final(
    const float* __restrict__ bsum, const float* __restrict__ bcnt,
    float* __restrict__ out, int nb) {
  const int t = threadIdx.x;
  float s = (t < nb) ? bsum[t] : 0.f;
  float c = (t < nb) ? bcnt[t] : 0.f;
#pragma unroll
  for (int off = 32; off; off >>= 1) {
    s += __shfl_down(s, off);
    c += __shfl_down(c, off);
  }
  if (t == 0) out[0] = (c > 0.f) ? s / c : 0.f;
}

extern "C" void kernel_launch(void* const* d_in, const int* in_sizes, int n_in,
                              void* d_out, int out_size, void* d_ws, size_t ws_size,
                              hipStream_t stream) {
  const float* A = (const float*)d_in[0];
  const float* P = (const float*)d_in[1];
  const int* labels = (const int*)d_in[2];
  float* out = (float*)d_out;
  const int B = in_sizes[2];
  const int D = in_sizes[0] / B;
  const int NN = 2 * B;

  char* ws = (char*)d_ws;
  unsigned char* F = (unsigned char*)ws;
  size_t off = (size_t)NN * D;  // fp8: 1 B/elem
  off = (off + 255) & ~(size_t)255;
  float* cross = (float*)(ws + off);
  off += (size_t)B * sizeof(float);
  off = (off + 255) & ~(size_t)255;
  float* lsum = (float*)(ws + off);
  off += (size_t)NN * sizeof(float);
  off = (off + 255) & ~(size_t)255;
  float* bsum = (float*)(ws + off);
  off += 64 * sizeof(float);
  float* bcnt = (float*)(ws + off);

  norm_kernel<<<B, 256, 0, stream>>>(A, P, F, cross, lsum, B, D);
  // 528 triangle tiles in ONE dispatch: 512 blocks, first 16 take 2 tiles
  gram_full_kernel<<<512, 1024, 0, stream>>>(F, lsum, NN, D);
  const int nb = (NN + 255) / 256;  // 32
  finalize_part<<<nb, 256, 0, stream>>>(lsum, cross, labels, bsum, bcnt, B);
  finalize_final<<<1, 64, 0, stream>>>(bsum, bcnt, out, nb);
}